// Round 1
// 97.266 us; speedup vs baseline: 1.0422x; 1.0422x over previous
//
#include <hip/hip_runtime.h>
#include <hip/hip_bf16.h>

// Problem constants (fixed by reference): B=4, C=64, H=W=64, N=4096
#define BATCH 4
#define NSP   4096

// (1/64)*sqrt(log2 e): both Q and K carry this, so S^T = score*log2e/4096 and
// softmax uses raw v_exp_f32 (2^x) with no per-element multiply.
#define QKSCALE 0.0187675376f

typedef __bf16 bf16x8v __attribute__((ext_vector_type(8)));
typedef __bf16 bf16x4v __attribute__((ext_vector_type(4)));
typedef short  shortx4 __attribute__((ext_vector_type(4)));
typedef float  floatx4 __attribute__((ext_vector_type(4)));

static __device__ __forceinline__ shortx4 bf4_bits(bf16x4v v) {
    union { bf16x4v b; shortx4 s; } u; u.b = v; return u.s;
}

static __device__ __forceinline__ float fast_exp2(float x) {
#if __has_builtin(__builtin_amdgcn_exp2f)
    return __builtin_amdgcn_exp2f(x);
#else
    return exp2f(x);
#endif
}

// PV MFMA: 16x16x16 bf16. Its B-operand layout B[k=quad*4+r][col=l16] matches
// the S^T MFMA's D layout exactly, so exp() results feed PV straight from
// registers -- no P round-trip through LDS.
static __device__ __forceinline__ floatx4 mfma_pv(shortx4 a, shortx4 b, floatx4 c) {
#if __has_builtin(__builtin_amdgcn_mfma_f32_16x16x16bf16_1k)
    return __builtin_amdgcn_mfma_f32_16x16x16bf16_1k(a, b, c, 0, 0, 0);
#else
    floatx4 d;
    asm("v_mfma_f32_16x16x16_bf16 %0, %1, %2, %3" : "=&v"(d) : "v"(a), "v"(b), "v"(c));
    return d;
#endif
}

// ---------------------------------------------------------------------------
// Kernel 1: qkT[b][n][o] = bf16( (sum_c W[o][c]*x[b][c][n] + bias[o]) * s ),
// s = QKSCALE (exp2 folding). Also emits xbf = bf16(x) so the attention
// kernel's V staging is a pure uint4 copy (half the bytes, zero cvt VALU).
// ---------------------------------------------------------------------------
__global__ __launch_bounds__(256) void qk_kernel(const float* __restrict__ x,
                                                 const float* __restrict__ Wm,
                                                 const float* __restrict__ bias,
                                                 __bf16* __restrict__ qkT,
                                                 __bf16* __restrict__ xbf) {
    __shared__ __align__(16) __bf16 xT[64 * 72];   // [n][c]; reused as [n][o] out buf

    const int t  = threadIdx.x;
    const int b  = blockIdx.x >> 6;
    const int n0 = (blockIdx.x & 63) << 6;

    // stage x^T tile, pre-scaled, coalesced float4 reads; also write bf16 V copy
#pragma unroll
    for (int p = 0; p < 4; ++p) {
        const int c  = p * 16 + (t >> 4);
        const int n4 = (t & 15) * 4;
        const float4 v = *(const float4*)(x + (size_t)(b * 64 + c) * 4096 + n0 + n4);
        xT[(n4 + 0) * 72 + c] = (__bf16)(v.x * QKSCALE);
        xT[(n4 + 1) * 72 + c] = (__bf16)(v.y * QKSCALE);
        xT[(n4 + 2) * 72 + c] = (__bf16)(v.z * QKSCALE);
        xT[(n4 + 3) * 72 + c] = (__bf16)(v.w * QKSCALE);
        bf16x4v xv;
        xv[0] = (__bf16)v.x; xv[1] = (__bf16)v.y; xv[2] = (__bf16)v.z; xv[3] = (__bf16)v.w;
        *(bf16x4v*)(xbf + (size_t)(b * 64 + c) * 4096 + n0 + n4) = xv;
    }
    __syncthreads();

    const int w = t >> 6, lane = t & 63, quad = lane >> 4, l16 = lane & 15;
    // A-frags: A[n=l16][c=quad*8+j], wave w owns n-rows w*16..+15
    const bf16x8v a0 = *(const bf16x8v*)(xT + (w * 16 + l16) * 72 + quad * 8);
    const bf16x8v a1 = *(const bf16x8v*)(xT + (w * 16 + l16) * 72 + 32 + quad * 8);

    floatx4 acc[4];
#pragma unroll
    for (int ot = 0; ot < 4; ++ot) {
        // B-frags straight from global W (fp32 -> bf16): B[k=c][n=o], o=ot*16+l16
        const float* wr = Wm + (ot * 16 + l16) * 64;
        float4 wa = *(const float4*)(wr + quad * 8);
        float4 wb = *(const float4*)(wr + quad * 8 + 4);
        float4 wc = *(const float4*)(wr + 32 + quad * 8);
        float4 wd = *(const float4*)(wr + 32 + quad * 8 + 4);
        bf16x8v b0, b1;
        b0[0]=(__bf16)wa.x; b0[1]=(__bf16)wa.y; b0[2]=(__bf16)wa.z; b0[3]=(__bf16)wa.w;
        b0[4]=(__bf16)wb.x; b0[5]=(__bf16)wb.y; b0[6]=(__bf16)wb.z; b0[7]=(__bf16)wb.w;
        b1[0]=(__bf16)wc.x; b1[1]=(__bf16)wc.y; b1[2]=(__bf16)wc.z; b1[3]=(__bf16)wc.w;
        b1[4]=(__bf16)wd.x; b1[5]=(__bf16)wd.y; b1[6]=(__bf16)wd.z; b1[7]=(__bf16)wd.w;
        acc[ot] = floatx4{0.f, 0.f, 0.f, 0.f};
        acc[ot] = __builtin_amdgcn_mfma_f32_16x16x32_bf16(a0, b0, acc[ot], 0, 0, 0);
        acc[ot] = __builtin_amdgcn_mfma_f32_16x16x32_bf16(a1, b1, acc[ot], 0, 0, 0);
    }
    __syncthreads();   // all xT frag reads done before reuse as [n][o]

    // D: row(quad*4+r)=n_local within wave's 16-n, col(l16)=o_local
#pragma unroll
    for (int ot = 0; ot < 4; ++ot) {
        const float bo = bias[ot * 16 + l16] * QKSCALE;
#pragma unroll
        for (int r = 0; r < 4; ++r)
            xT[(w * 16 + quad * 4 + r) * 72 + ot * 16 + l16] = (__bf16)(acc[ot][r] + bo);
    }
    __syncthreads();

    const int n = t >> 2, seg = t & 3;
    __bf16* dst = qkT + (size_t)(b * 4096 + n0 + n) * 64 + seg * 16;
    *(bf16x8v*)dst       = *(const bf16x8v*)(xT + n * 72 + seg * 16);
    *(bf16x8v*)(dst + 8) = *(const bf16x8v*)(xT + n * 72 + seg * 16 + 8);
}

// ---------------------------------------------------------------------------
// Kernel 2: flash-style attention. Block = (b, 128-q tile, m-chunk), 4 waves
// x 32 q. Restructured vs R4:
//  * K and V tiles double-buffered in LDS -> ONE barrier per iter, with
//    global->reg prefetch issued before the barrier (latency hidden).
//  * P stays in registers: S^T D-layout == 16x16x16 PV B-layout.
//  * V staged bf16 from xbf (uint4 copies, no cvt).
//  * exp2 instead of exp (scale folded in qk_kernel).
// LDS: Kdbuf 2x9216 + Vdbuf 2x9216 = 36864 -> 4 blocks/CU.
// ---------------------------------------------------------------------------
template<int SPLIT, int ITERS>
__global__ __launch_bounds__(256, 4) void attn_kernel(const __bf16* __restrict__ xbf,
                                                      const __bf16* __restrict__ qkT,
                                                      __bf16* __restrict__ Opart,
                                                      float* __restrict__ Lpart) {
    __shared__ __align__(16) char smem[36864];
    __bf16* Klds = (__bf16*)smem;                 // [2][64 m][72 c]
    __bf16* Vlds = (__bf16*)(smem + 18432);       // [2][64 c][72 m]
    float*  Olds = (float*)smem;                  // epilogue alias: [64 c][132 q]

    const int t   = threadIdx.x;
    const int blk = blockIdx.x;
    const int xcd = blk & 7;                      // XCD round-robin
    const int b   = xcd >> 1;                     // each b pinned to 2 XCDs
    const int sub = ((blk >> 3) << 1) | (xcd & 1);
    const int qt  = sub / SPLIT;
    const int s   = sub % SPLIT;
    const int n0  = qt << 7;
    const int pblk = (b * 32 + qt) * SPLIT + s;

    const int w = t >> 6, lane = t & 63, quad = lane >> 4, l16 = lane & 15;

    const __bf16* kgl = qkT + (size_t)b * 4096 * 64;   // [n][c] bf16
    const __bf16* vgl = xbf + (size_t)b * 64 * 4096;   // [c][n] bf16

    // Q B-frags: B[k=c][q], q = w*32 + qt2*16 + l16
    bf16x8v fq[2][2];
#pragma unroll
    for (int qt2 = 0; qt2 < 2; ++qt2) {
        const __bf16* qrow = kgl + (size_t)(n0 + w * 32 + qt2 * 16 + l16) * 64;
        fq[qt2][0] = *(const bf16x8v*)(qrow + quad * 8);
        fq[qt2][1] = *(const bf16x8v*)(qrow + 32 + quad * 8);
    }

    // oacc[qt2][ct]: D[c_local=quad*4+r][q=l16] (c rows, q cols)
    floatx4 oacc[2][4];
#pragma unroll
    for (int i = 0; i < 2; ++i)
#pragma unroll
        for (int j = 0; j < 4; ++j) oacc[i][j] = floatx4{0.f, 0.f, 0.f, 0.f};
    float rs[2] = {0.f, 0.f};

    // staging: 2 K-granules + 2 V-granules per thread (16B each)
    const int srow = t >> 3;            // 0..31
    const int sg   = (t & 7) * 8;       // bf16 granule offset
    uint4 kst0, kst1, vst0, vst1;
    auto stage_load = [&](int m0) {
        kst0 = *(const uint4*)(kgl + (size_t)(m0 + srow) * 64 + sg);
        kst1 = *(const uint4*)(kgl + (size_t)(m0 + srow + 32) * 64 + sg);
        vst0 = *(const uint4*)(vgl + (size_t)srow * 4096 + m0 + sg);
        vst1 = *(const uint4*)(vgl + (size_t)(srow + 32) * 4096 + m0 + sg);
    };
    auto stage_write = [&](int buf) {
        __bf16* kd = Klds + buf * 4608;
        __bf16* vd = Vlds + buf * 4608;
        *(uint4*)(kd + srow * 72 + sg)        = kst0;
        *(uint4*)(kd + (srow + 32) * 72 + sg) = kst1;
        *(uint4*)(vd + srow * 72 + sg)        = vst0;
        *(uint4*)(vd + (srow + 32) * 72 + sg) = vst1;
    };

    const int mbase = s * (64 * ITERS);
    stage_load(mbase);
    stage_write(0);
    int cur = 0;

    for (int it = 0; it < ITERS; ++it) {
        const int m0 = mbase + (it << 6);
        if (it + 1 < ITERS) stage_load(m0 + 64);   // prefetch next tile into regs
        __syncthreads();                           // cur buffers visible
        const __bf16* Kc = Klds + cur * 4608;
        const __bf16* Vc = Vlds + cur * 4608;

#pragma unroll
        for (int mt = 0; mt < 4; ++mt) {
            // S^T = K.Q^T: D row = m_local = quad*4+r, col = q = l16
            const __bf16* kr = Kc + (mt * 16 + l16) * 72;
            bf16x8v ak0 = *(const bf16x8v*)(kr + quad * 8);
            bf16x8v ak1 = *(const bf16x8v*)(kr + 32 + quad * 8);
            shortx4 pk[2];
#pragma unroll
            for (int qt2 = 0; qt2 < 2; ++qt2) {
                floatx4 sT = {0.f, 0.f, 0.f, 0.f};
                sT = __builtin_amdgcn_mfma_f32_16x16x32_bf16(ak0, fq[qt2][0], sT, 0, 0, 0);
                sT = __builtin_amdgcn_mfma_f32_16x16x32_bf16(ak1, fq[qt2][1], sT, 0, 0, 0);
                float p0 = fast_exp2(sT[0]), p1 = fast_exp2(sT[1]);
                float p2 = fast_exp2(sT[2]), p3 = fast_exp2(sT[3]);
                rs[qt2] += (p0 + p1) + (p2 + p3);
                bf16x4v pv;
                pv[0] = (__bf16)p0; pv[1] = (__bf16)p1; pv[2] = (__bf16)p2; pv[3] = (__bf16)p3;
                pk[qt2] = bf4_bits(pv);            // B[k=m=quad*4+r][col=q=l16]
            }
            // O[c][q] += V[c][m] * P^T[m][q], K=16 per mt, P straight from regs
#pragma unroll
            for (int ct = 0; ct < 4; ++ct) {
                shortx4 av = *(const shortx4*)(Vc + (ct * 16 + l16) * 72 + mt * 16 + quad * 4);
                oacc[0][ct] = mfma_pv(av, pk[0], oacc[0][ct]);
                oacc[1][ct] = mfma_pv(av, pk[1], oacc[1][ct]);
            }
        }

        if (it + 1 < ITERS) stage_write(cur ^ 1);  // vmcnt wait lands here (hidden)
        cur ^= 1;
    }

#pragma unroll
    for (int qt2 = 0; qt2 < 2; ++qt2) {
        float v = rs[qt2];
        v += __shfl_xor(v, 16, 64);
        v += __shfl_xor(v, 32, 64);
        if (quad == 0)
            Lpart[(size_t)pblk * 128 + w * 32 + qt2 * 16 + l16] = v;
    }

    __syncthreads();   // all K/V LDS reads done before reuse as Olds

    // oacc D: row = c_local = quad*4+r, col = q = l16
#pragma unroll
    for (int qt2 = 0; qt2 < 2; ++qt2)
#pragma unroll
        for (int ct = 0; ct < 4; ++ct)
#pragma unroll
            for (int r = 0; r < 4; ++r)
                Olds[(ct * 16 + quad * 4 + r) * 132 + w * 32 + qt2 * 16 + l16] = oacc[qt2][ct][r];
    __syncthreads();

    const int c = t >> 2, seg = t & 3;
#pragma unroll
    for (int i = 0; i < 4; ++i) {
        floatx4 v0 = *(const floatx4*)(Olds + c * 132 + seg * 32 + i * 8);
        floatx4 v1 = *(const floatx4*)(Olds + c * 132 + seg * 32 + i * 8 + 4);
        bf16x8v pk;
        pk[0]=(__bf16)v0[0]; pk[1]=(__bf16)v0[1]; pk[2]=(__bf16)v0[2]; pk[3]=(__bf16)v0[3];
        pk[4]=(__bf16)v1[0]; pk[5]=(__bf16)v1[1]; pk[6]=(__bf16)v1[2]; pk[7]=(__bf16)v1[3];
        *(bf16x8v*)(Opart + (size_t)pblk * 8192 + c * 128 + seg * 32 + i * 8) = pk;
    }
}

// ---------------------------------------------------------------------------
// Kernel 3: combine SPLIT m-chunk partials, normalize, store fp32 output.
// 512 blocks x 256 thr; 16B Opart loads, 8-deep MLP.
// ---------------------------------------------------------------------------
template<int SPLIT>
__global__ __launch_bounds__(256) void reduce_kernel(const __bf16* __restrict__ Opart,
                                                     const float* __restrict__ Lpart,
                                                     float* __restrict__ out) {
    const int blk = blockIdx.x;           // (b*32+qt)*4 + cq
    const int bq = blk >> 2, cq = blk & 3;
    const int b = bq >> 5, qt = bq & 31;
    const int t = threadIdx.x;
    const int c  = cq * 16 + (t >> 4);     // channel
    const int q8 = (t & 15) * 8;           // q offset (8 per thread)

    float l[8] = {0.f,0.f,0.f,0.f,0.f,0.f,0.f,0.f};
#pragma unroll
    for (int s = 0; s < SPLIT; ++s) {
        const float* lp = Lpart + ((size_t)bq * SPLIT + s) * 128 + q8;
        float4 u = *(const float4*)lp;
        float4 v = *(const float4*)(lp + 4);
        l[0]+=u.x; l[1]+=u.y; l[2]+=u.z; l[3]+=u.w;
        l[4]+=v.x; l[5]+=v.y; l[6]+=v.z; l[7]+=v.w;
    }
    float a[8] = {0.f,0.f,0.f,0.f,0.f,0.f,0.f,0.f};
#pragma unroll
    for (int s = 0; s < SPLIT; ++s) {
        bf16x8v v = *(const bf16x8v*)(Opart + ((size_t)bq * SPLIT + s) * 8192 + c * 128 + q8);
#pragma unroll
        for (int k = 0; k < 8; ++k) a[k] += (float)v[k];
    }
    float* op = out + (size_t)(b * 64 + c) * 4096 + qt * 128 + q8;
    float4 o0, o1;
    o0.x = a[0]/l[0]; o0.y = a[1]/l[1]; o0.z = a[2]/l[2]; o0.w = a[3]/l[3];
    o1.x = a[4]/l[4]; o1.y = a[5]/l[5]; o1.z = a[6]/l[6]; o1.w = a[7]/l[7];
    *(float4*)op       = o0;
    *(float4*)(op + 4) = o1;
}

// ---------------------------------------------------------------------------
extern "C" void kernel_launch(void* const* d_in, const int* in_sizes, int n_in,
                              void* d_out, int out_size, void* d_ws, size_t ws_size,
                              hipStream_t stream) {
    const float* x    = (const float*)d_in[0];   // [4][64][4096]
    const float* Wm   = (const float*)d_in[1];   // [64][64]
    const float* bias = (const float*)d_in[2];   // [64]
    float* out = (float*)d_out;                  // [4][64][4096]

    char* ws = (char*)d_ws;
    __bf16* qkT = (__bf16*)ws;                   // 2 MB [4][4096][64] bf16
    __bf16* xbf = (__bf16*)(ws + 2097152);       // 2 MB [4][64][4096] bf16

    qk_kernel<<<BATCH * (NSP / 64), 256, 0, stream>>>(x, Wm, bias, qkT, xbf);

    const size_t HEAD = 2097152 + 2097152;
    const size_t needBig = HEAD + (size_t)1024 * 8192 * 2 + (size_t)1024 * 128 * 4;  // ~21.5 MB
    if (ws_size >= needBig) {
        __bf16* Opart = (__bf16*)(ws + HEAD);                          // 16 MB [1024][64][128]
        float*  Lpart = (float*)(ws + HEAD + (size_t)1024 * 8192 * 2); // 512 KB
        attn_kernel<8, 8><<<BATCH * 32 * 8, 256, 0, stream>>>(xbf, qkT, Opart, Lpart);
        reduce_kernel<8><<<512, 256, 0, stream>>>(Opart, Lpart, out);
    } else {
        __bf16* Opart = (__bf16*)(ws + HEAD);                          // 8 MB [512][64][128]
        float*  Lpart = (float*)(ws + HEAD + (size_t)512 * 8192 * 2);  // 256 KB
        attn_kernel<4, 16><<<BATCH * 32 * 4, 256, 0, stream>>>(xbf, qkT, Opart, Lpart);
        reduce_kernel<4><<<512, 256, 0, stream>>>(Opart, Lpart, out);
    }
}